// Round 6
// baseline (304.674 us; speedup 1.0000x reference)
//
#include <hip/hip_runtime.h>
#include <hip/hip_bf16.h>

#define NN 50000
#define NE 800000
#define NB 196          // ceil(NN/256)
#define NROWPAD 50048   // 128-row padded so GEMM A reads stay in-bounds

#define XCVT_BLOCKS 6250    // NN*256/8/256
#define TW_BLOCKS   192     // 8*8*3
#define HIST_BLOCKS 3125    // ceil(NE/256)

typedef __attribute__((ext_vector_type(8))) short short8;
typedef __attribute__((ext_vector_type(4))) float floatx4;
typedef unsigned short u16;
typedef unsigned int u32;

__device__ __forceinline__ u16 f2bf(float f) {
    u32 u = __float_as_uint(f);
    u += 0x7FFFu + ((u >> 16) & 1u);   // RNE
    return (u16)(u >> 16);
}
__device__ __forceinline__ float bf_lo(u32 u) { return __uint_as_float(u << 16); }
__device__ __forceinline__ float bf_hi(u32 u) { return __uint_as_float(u & 0xFFFF0000u); }
__device__ __forceinline__ u32 pack_bf(float lo, float hi) {
    return (u32)f2bf(lo) | ((u32)f2bf(hi) << 16);
}
__device__ __forceinline__ void gl_lds16(const void* g, void* l) {
    __builtin_amdgcn_global_load_lds((const __attribute__((address_space(1))) void*)g,
                                     (__attribute__((address_space(3))) void*)l, 16, 0, 0);
}

#if __has_builtin(__builtin_amdgcn_exp2f)
#define EXP2F(x) __builtin_amdgcn_exp2f(x)
#else
#define EXP2F(x) exp2f(x)
#endif

// =============== prep: xcvt (x->bf16) + W/U/V transpose + degree histogram ===============
__global__ __launch_bounds__(256) void prep_kernel(
    const float* __restrict__ x, u16* __restrict__ xbf,
    const float* __restrict__ W, const float* __restrict__ U, const float* __restrict__ V,
    u16* __restrict__ wT, const int* __restrict__ dst, int* __restrict__ deg, int do_xcvt) {
    __shared__ float s[32][33];
    int b = blockIdx.x;
    int xb = do_xcvt ? XCVT_BLOCKS : 0;
    if (b < xb) {
        size_t i = ((size_t)b * 256 + threadIdx.x) * 8;
        floatx4 f0 = *(const floatx4*)(x + i);
        floatx4 f1 = *(const floatx4*)(x + i + 4);
        uint4 pk;
        pk.x = pack_bf(f0[0], f0[1]);
        pk.y = pack_bf(f0[2], f0[3]);
        pk.z = pack_bf(f1[0], f1[1]);
        pk.w = pack_bf(f1[2], f1[3]);
        *(uint4*)(xbf + i) = pk;
    } else if (b < xb + TW_BLOCKS) {
        int bb = b - xb;
        int g = bb >> 6, rem = bb & 63;
        int r0 = (rem & 7) * 32, c0 = (rem >> 3) * 32;
        const float* M = (g == 0) ? W : ((g == 1) ? U : V);
        int tx = threadIdx.x & 31, ty = threadIdx.x >> 5;   // 32 x 8
#pragma unroll
        for (int k = 0; k < 4; ++k)
            s[ty + k * 8][tx] = M[(size_t)(r0 + ty + k * 8) * 256 + c0 + tx];
        __syncthreads();
#pragma unroll
        for (int k = 0; k < 4; ++k)
            wT[(size_t)(g * 256 + c0 + ty + k * 8) * 256 + r0 + tx] = f2bf(s[tx][ty + k * 8]);
    } else {
        int e = (b - xb - TW_BLOCKS) * 256 + threadIdx.x;
        if (e < NE) atomicAdd(&deg[dst[e]], 1);
    }
}

// ---------------- 3-phase scan ----------------
__global__ __launch_bounds__(256) void scanA_kernel(const int* __restrict__ deg, int* __restrict__ bsum) {
    int t = threadIdx.x;
    int i = blockIdx.x * 256 + t;
    int v = (i < NN) ? deg[i] : 0;
#pragma unroll
    for (int m = 32; m; m >>= 1) v += __shfl_xor(v, m, 64);
    __shared__ int ws[4];
    if ((t & 63) == 0) ws[t >> 6] = v;
    __syncthreads();
    if (t == 0) bsum[blockIdx.x] = ws[0] + ws[1] + ws[2] + ws[3];
}

__global__ __launch_bounds__(256) void scanB_kernel(const int* __restrict__ bsum, int* __restrict__ bpre,
                                                    int* __restrict__ rows_end) {
    int t = threadIdx.x, lane = t & 63, wv = t >> 6;
    int v = (t < NB) ? bsum[t] : 0;
    int inc = v;
#pragma unroll
    for (int off = 1; off < 64; off <<= 1) {
        int u = __shfl_up(inc, off, 64);
        if (lane >= off) inc += u;
    }
    __shared__ int wsum[4];
    if (lane == 63) wsum[wv] = inc;
    __syncthreads();
    int woff = 0;
    for (int k = 0; k < wv; ++k) woff += wsum[k];
    if (t < NB) bpre[t] = woff + inc - v;
    if (t == 255) rows_end[0] = woff + inc;
}

__global__ __launch_bounds__(256) void scanC_kernel(const int* __restrict__ deg, const int* __restrict__ bpre,
                                                    int* __restrict__ rows, int* __restrict__ cursor) {
    int t = threadIdx.x, lane = t & 63, wv = t >> 6;
    int i = blockIdx.x * 256 + t;
    int v = (i < NN) ? deg[i] : 0;
    int inc = v;
#pragma unroll
    for (int off = 1; off < 64; off <<= 1) {
        int u = __shfl_up(inc, off, 64);
        if (lane >= off) inc += u;
    }
    __shared__ int wsum[4];
    if (lane == 63) wsum[wv] = inc;
    __syncthreads();
    int woff = bpre[blockIdx.x];
    for (int k = 0; k < wv; ++k) woff += wsum[k];
    int excl = woff + inc - v;
    if (i < NN) { rows[i] = excl; cursor[i] = excl; }
}

// ---------------- scatter edges into CSR-by-dst (own kernel: no LDS, high occupancy) --------
__global__ void scatter_kernel(const int* __restrict__ src, const int* __restrict__ dst,
                               int* __restrict__ cursor, int* __restrict__ esrc) {
    int e = blockIdx.x * 256 + threadIdx.x;
    if (e < NE) {
        int d = dst[e];
        int pos = atomicAdd(&cursor[d], 1);
        esrc[pos] = src[e];
    }
}

// =============== GEMM v2: B-stationary LDS (128 cols x K=256), A in registers ===============
// block = 128 rows x 128 cols; 4 waves x 32 rows. ONE barrier total.
// LDS Bs[col][k] u16, 64KB. Staged via gl_lds16 with involutive quad-XOR source swizzle:
//   LDS (col, quad qL) holds global quad qL ^ (col&7); reader XORs the same way.
template<bool USE_BF>
__global__ __launch_bounds__(256, 2) void gemm2_kernel(
    const u16* __restrict__ xbf, const float* __restrict__ xf, const u16* __restrict__ wT,
    const float* __restrict__ Wb, const float* __restrict__ Ub, const float* __restrict__ Vb,
    u16* __restrict__ WVh, float* __restrict__ Uh) {
    __shared__ __align__(16) u16 Bs[128 * 256];   // 64 KB

    int rb = blockIdx.x * 128;
    int cgy = blockIdx.y;                 // 0..5, 128 cols each
    int cbg = cgy * 128;                  // global col base in [0,768)
    int t = threadIdx.x, lane = t & 63, w = t >> 6;

    // ---- A: 16 fragments (2 row-groups x 8 k-steps) straight to VGPRs ----
    int arow = rb + w * 32 + (lane & 15);
    short8 afr[2][8];
    if (USE_BF) {
#pragma unroll
        for (int rg = 0; rg < 2; ++rg)
#pragma unroll
            for (int ks = 0; ks < 8; ++ks)
                afr[rg][ks] = *(const short8*)(xbf + (size_t)(arow + rg * 16) * 256 + ks * 32 + (lane >> 4) * 8);
    } else {
#pragma unroll
        for (int rg = 0; rg < 2; ++rg)
#pragma unroll
            for (int ks = 0; ks < 8; ++ks) {
                int row = arow + rg * 16;
                const float* p = xf + ((size_t)(row < NN ? row : 0)) * 256 + ks * 32 + (lane >> 4) * 8;
                floatx4 f0 = *(const floatx4*)(p);
                floatx4 f1 = *(const floatx4*)(p + 4);
                uint4 pk;
                pk.x = pack_bf(f0[0], f0[1]);
                pk.y = pack_bf(f0[2], f0[3]);
                pk.z = pack_bf(f1[0], f1[1]);
                pk.w = pack_bf(f1[2], f1[3]);
                afr[rg][ks] = *(short8*)&pk;
            }
    }

    // ---- B: stage 64KB once; each gl_lds16 covers 1KB = 2 cols (512B each) ----
#pragma unroll
    for (int i = 0; i < 16; ++i) {
        int ci = (w * 16 + i) * 2 + (lane >> 5);           // col 0..127
        int q = (lane & 31) ^ (ci & 7);                    // source quad (involution)
        gl_lds16(wT + (size_t)(cbg + ci) * 256 + q * 8, Bs + (w * 16 + i) * 512);
    }
    __syncthreads();

    // ---- compute: 64 ds_read_b128, 128 MFMA per wave, no barriers ----
    floatx4 acc[2][8] = {};
#pragma unroll
    for (int ks = 0; ks < 8; ++ks) {
#pragma unroll
        for (int cf = 0; cf < 8; ++cf) {
            int ci = cf * 16 + (lane & 15);
            int q = (ks * 4 + (lane >> 4)) ^ (ci & 7);
            short8 bfrag = *(const short8*)(Bs + ci * 256 + q * 8);
            acc[0][cf] = __builtin_amdgcn_mfma_f32_16x16x32_bf16(afr[0][ks], bfrag, acc[0][cf], 0, 0, 0);
            acc[1][cf] = __builtin_amdgcn_mfma_f32_16x16x32_bf16(afr[1][ks], bfrag, acc[1][cf], 0, 0, 0);
        }
    }

    // ---- epilogue ----
    int g = cbg >> 8;                    // 0,0,1,1,2,2
    int cloc = cbg & 255;                // 0 or 128
    const float* bias = (g == 0) ? Wb : ((g == 1) ? Ub : Vb);
#pragma unroll
    for (int rg = 0; rg < 2; ++rg)
#pragma unroll
        for (int cf = 0; cf < 8; ++cf) {
            int col = cloc + cf * 16 + (lane & 15);
            float bv = bias[col];
#pragma unroll
            for (int r = 0; r < 4; ++r) {
                int row = rb + w * 32 + rg * 16 + (lane >> 4) * 4 + r;
                if (row < NN) {
                    float val = acc[rg][cf][r] + bv;
                    if (g == 0)      WVh[(size_t)row * 512 + col] = f2bf(val);
                    else if (g == 1) Uh[(size_t)row * 256 + col] = val;
                    else             WVh[(size_t)row * 512 + 256 + col] = f2bf(val);
                }
            }
        }
}

// ---------------- node-centric aggregate + LN + ReLU + residual ----------------
__global__ __launch_bounds__(256) void node_kernel(
    const u16* __restrict__ WVh, const float* __restrict__ x,
    const int* __restrict__ rows, const int* __restrict__ esrc,
    const float* __restrict__ attn_l, const float* __restrict__ attn_r,
    const float* __restrict__ gamma, const float* __restrict__ beta,
    float* inout) {
    int wv = threadIdx.x >> 6, lane = threadIdx.x & 63;
    int v = blockIdx.x * 4 + wv;
    if (v >= NN) return;
    int c0 = lane * 4;

    const float NL2E = -1.44269504f;    // -log2(e)
    floatx4 alv = *(const floatx4*)(attn_l + c0);
    floatx4 arv = *(const floatx4*)(attn_r + c0);
    uint2 wvv = *(const uint2*)(WVh + (size_t)v * 512 + c0);
    float al2[4] = { alv[0] * NL2E, alv[1] * NL2E, alv[2] * NL2E, alv[3] * NL2E };
    float td2[4] = { bf_lo(wvv.x) * arv[0] * NL2E, bf_hi(wvv.x) * arv[1] * NL2E,
                     bf_lo(wvv.y) * arv[2] * NL2E, bf_hi(wvv.y) * arv[3] * NL2E };

    float acc_h[4] = {0.f, 0.f, 0.f, 0.f};
    float acc_s[4] = {0.f, 0.f, 0.f, 0.f};

    auto edge = [&](uint2 wu, uint2 vu) {
        float wf[4] = { bf_lo(wu.x), bf_hi(wu.x), bf_lo(wu.y), bf_hi(wu.y) };
        float vf[4] = { bf_lo(vu.x), bf_hi(vu.x), bf_lo(vu.y), bf_hi(vu.y) };
#pragma unroll
        for (int j = 0; j < 4; ++j) {
            float m = fmaf(wf[j], al2[j], td2[j]);
            float s = __builtin_amdgcn_rcpf(1.0f + EXP2F(m));
            acc_s[j] += s;
            acc_h[j] = fmaf(s, vf[j], acc_h[j]);
        }
    };

    int e = rows[v], e1 = rows[v + 1];
    for (; e + 8 <= e1; e += 8) {
        int us[8];
#pragma unroll
        for (int q = 0; q < 8; ++q) us[q] = esrc[e + q];
        uint2 wu[8], vu[8];
#pragma unroll
        for (int q = 0; q < 8; ++q) {
            const u16* p = WVh + (size_t)us[q] * 512 + c0;
            wu[q] = *(const uint2*)p;
            vu[q] = *(const uint2*)(p + 256);
        }
#pragma unroll
        for (int q = 0; q < 8; ++q) edge(wu[q], vu[q]);
    }
    for (; e + 2 <= e1; e += 2) {
        int ua = esrc[e], ub = esrc[e + 1];
        const u16* pa = WVh + (size_t)ua * 512 + c0;
        const u16* pb = WVh + (size_t)ub * 512 + c0;
        uint2 wa = *(const uint2*)pa, va = *(const uint2*)(pa + 256);
        uint2 wb = *(const uint2*)pb, vb = *(const uint2*)(pb + 256);
        edge(wa, va); edge(wb, vb);
    }
    for (; e < e1; ++e) {
        int u = esrc[e];
        const u16* p = WVh + (size_t)u * 512 + c0;
        uint2 wu = *(const uint2*)p, vu = *(const uint2*)(p + 256);
        edge(wu, vu);
    }

    floatx4 uh = *(const floatx4*)(inout + (size_t)v * 256 + c0);
    float h[4];
#pragma unroll
    for (int j = 0; j < 4; ++j)
        h[j] = uh[j] + acc_h[j] * __builtin_amdgcn_rcpf(acc_s[j] + 1e-6f);

    float s01 = h[0] + h[1] + h[2] + h[3];
#pragma unroll
    for (int m = 32; m; m >>= 1) s01 += __shfl_xor(s01, m, 64);
    float mu = s01 * (1.0f / 256.0f);
    float d[4] = { h[0] - mu, h[1] - mu, h[2] - mu, h[3] - mu };
    float sq = d[0] * d[0] + d[1] * d[1] + d[2] * d[2] + d[3] * d[3];
#pragma unroll
    for (int m = 32; m; m >>= 1) sq += __shfl_xor(sq, m, 64);
    float inv = rsqrtf(sq * (1.0f / 256.0f) + 1e-6f);

    floatx4 gm = *(const floatx4*)(gamma + c0);
    floatx4 bt = *(const floatx4*)(beta + c0);
    floatx4 xr = *(const floatx4*)(x + (size_t)v * 256 + c0);
    floatx4 res;
#pragma unroll
    for (int j = 0; j < 4; ++j) {
        float y = d[j] * inv * gm[j] + bt[j];
        y = fmaxf(y, 0.0f);
        res[j] = xr[j] + y;
    }
    *(floatx4*)(inout + (size_t)v * 256 + c0) = res;
}

extern "C" void kernel_launch(void* const* d_in, const int* in_sizes, int n_in,
                              void* d_out, int out_size, void* d_ws, size_t ws_size,
                              hipStream_t stream) {
    const float* x       = (const float*)d_in[0];
    const int*   src     = (const int*)d_in[1];
    const int*   dst     = (const int*)d_in[2];
    const float* W_w     = (const float*)d_in[3];
    const float* W_b     = (const float*)d_in[4];
    const float* U_w     = (const float*)d_in[5];
    const float* U_b     = (const float*)d_in[6];
    const float* V_w     = (const float*)d_in[7];
    const float* V_b     = (const float*)d_in[8];
    const float* attn_l  = (const float*)d_in[9];
    const float* attn_r  = (const float*)d_in[10];
    const float* gamma   = (const float*)d_in[11];
    const float* beta    = (const float*)d_in[12];

    char* ws = (char*)d_ws;
    size_t off = 0;
    auto alloc = [&](size_t bytes) -> char* {
        char* p = ws + off;
        off += (bytes + 255) & ~(size_t)255;
        return p;
    };
    u16* WVh     = (u16*)alloc((size_t)NN * 512 * 2);     // Wh | Vh interleaved per node
    u16* wT      = (u16*)alloc((size_t)768 * 256 * 2);
    int* deg     = (int*)alloc((size_t)NN * 4);
    int* rows    = (int*)alloc((size_t)(NN + 1) * 4);
    int* cursor  = (int*)alloc((size_t)NN * 4);
    int* esrc    = (int*)alloc((size_t)NE * 4);
    int* bsum    = (int*)alloc((size_t)NB * 4);
    int* bpre    = (int*)alloc((size_t)NB * 4);
    u16* xbf     = (u16*)alloc((size_t)NROWPAD * 256 * 2);   // optional (last)
    bool use_bf  = (ws_size >= off);

    float* Uh_f32 = (float*)d_out;   // staged in d_out, overwritten by node_kernel

    hipMemsetAsync(deg, 0, (size_t)NN * 4, stream);

    int xb = use_bf ? XCVT_BLOCKS : 0;
    prep_kernel<<<xb + TW_BLOCKS + HIST_BLOCKS, 256, 0, stream>>>(
        x, xbf, W_w, U_w, V_w, wT, dst, deg, use_bf ? 1 : 0);

    scanA_kernel<<<NB, 256, 0, stream>>>(deg, bsum);
    scanB_kernel<<<1, 256, 0, stream>>>(bsum, bpre, rows + NN);
    scanC_kernel<<<NB, 256, 0, stream>>>(deg, bpre, rows, cursor);
    scatter_kernel<<<(NE + 255) / 256, 256, 0, stream>>>(src, dst, cursor, esrc);

    dim3 gg((NN + 127) / 128, 6);
    if (use_bf) {
        gemm2_kernel<true><<<gg, 256, 0, stream>>>(xbf, x, wT, W_b, U_b, V_b, WVh, Uh_f32);
    } else {
        gemm2_kernel<false><<<gg, 256, 0, stream>>>(nullptr, x, wT, W_b, U_b, V_b, WVh, Uh_f32);
    }

    node_kernel<<<(NN + 3) / 4, 256, 0, stream>>>(
        WVh, x, rows, esrc, attn_l, attn_r, gamma, beta, (float*)d_out);
}

// Round 7
// 303.039 us; speedup vs baseline: 1.0054x; 1.0054x over previous
//
#include <hip/hip_runtime.h>
#include <hip/hip_bf16.h>

#define NN 50000
#define NE 800000
#define NB 196          // ceil(NN/256)
#define NROWPAD 50048   // 128-row padded so GEMM A reads stay in-bounds

#define XCVT_BLOCKS 6250    // NN*256/8/256
#define TW_BLOCKS   192     // 8*8*3
#define HIST_BLOCKS 3125    // ceil(NE/256)

typedef __attribute__((ext_vector_type(8))) short short8;
typedef __attribute__((ext_vector_type(4))) float floatx4;
typedef unsigned short u16;
typedef unsigned int u32;

__device__ __forceinline__ u16 f2bf(float f) {
    u32 u = __float_as_uint(f);
    u += 0x7FFFu + ((u >> 16) & 1u);   // RNE
    return (u16)(u >> 16);
}
__device__ __forceinline__ float bf_lo(u32 u) { return __uint_as_float(u << 16); }
__device__ __forceinline__ float bf_hi(u32 u) { return __uint_as_float(u & 0xFFFF0000u); }
__device__ __forceinline__ u32 pack_bf(float lo, float hi) {
    return (u32)f2bf(lo) | ((u32)f2bf(hi) << 16);
}
__device__ __forceinline__ void gl_lds16(const void* g, void* l) {
    __builtin_amdgcn_global_load_lds((const __attribute__((address_space(1))) void*)g,
                                     (__attribute__((address_space(3))) void*)l, 16, 0, 0);
}

#if __has_builtin(__builtin_amdgcn_exp2f)
#define EXP2F(x) __builtin_amdgcn_exp2f(x)
#else
#define EXP2F(x) exp2f(x)
#endif

// =============== prep: xcvt (x->bf16) + W/U/V transpose + degree histogram ===============
__global__ __launch_bounds__(256) void prep_kernel(
    const float* __restrict__ x, u16* __restrict__ xbf,
    const float* __restrict__ W, const float* __restrict__ U, const float* __restrict__ V,
    u16* __restrict__ wT, const int* __restrict__ dst, int* __restrict__ deg, int do_xcvt) {
    __shared__ float s[32][33];
    int b = blockIdx.x;
    int xb = do_xcvt ? XCVT_BLOCKS : 0;
    if (b < xb) {
        size_t i = ((size_t)b * 256 + threadIdx.x) * 8;
        floatx4 f0 = *(const floatx4*)(x + i);
        floatx4 f1 = *(const floatx4*)(x + i + 4);
        uint4 pk;
        pk.x = pack_bf(f0[0], f0[1]);
        pk.y = pack_bf(f0[2], f0[3]);
        pk.z = pack_bf(f1[0], f1[1]);
        pk.w = pack_bf(f1[2], f1[3]);
        *(uint4*)(xbf + i) = pk;
    } else if (b < xb + TW_BLOCKS) {
        int bb = b - xb;
        int g = bb >> 6, rem = bb & 63;
        int r0 = (rem & 7) * 32, c0 = (rem >> 3) * 32;
        const float* M = (g == 0) ? W : ((g == 1) ? U : V);
        int tx = threadIdx.x & 31, ty = threadIdx.x >> 5;   // 32 x 8
#pragma unroll
        for (int k = 0; k < 4; ++k)
            s[ty + k * 8][tx] = M[(size_t)(r0 + ty + k * 8) * 256 + c0 + tx];
        __syncthreads();
#pragma unroll
        for (int k = 0; k < 4; ++k)
            wT[(size_t)(g * 256 + c0 + ty + k * 8) * 256 + r0 + tx] = f2bf(s[tx][ty + k * 8]);
    } else {
        int e = (b - xb - TW_BLOCKS) * 256 + threadIdx.x;
        if (e < NE) atomicAdd(&deg[dst[e]], 1);
    }
}

// ---------------- 3-phase scan ----------------
__global__ __launch_bounds__(256) void scanA_kernel(const int* __restrict__ deg, int* __restrict__ bsum) {
    int t = threadIdx.x;
    int i = blockIdx.x * 256 + t;
    int v = (i < NN) ? deg[i] : 0;
#pragma unroll
    for (int m = 32; m; m >>= 1) v += __shfl_xor(v, m, 64);
    __shared__ int ws[4];
    if ((t & 63) == 0) ws[t >> 6] = v;
    __syncthreads();
    if (t == 0) bsum[blockIdx.x] = ws[0] + ws[1] + ws[2] + ws[3];
}

__global__ __launch_bounds__(256) void scanB_kernel(const int* __restrict__ bsum, int* __restrict__ bpre,
                                                    int* __restrict__ rows_end) {
    int t = threadIdx.x, lane = t & 63, wv = t >> 6;
    int v = (t < NB) ? bsum[t] : 0;
    int inc = v;
#pragma unroll
    for (int off = 1; off < 64; off <<= 1) {
        int u = __shfl_up(inc, off, 64);
        if (lane >= off) inc += u;
    }
    __shared__ int wsum[4];
    if (lane == 63) wsum[wv] = inc;
    __syncthreads();
    int woff = 0;
    for (int k = 0; k < wv; ++k) woff += wsum[k];
    if (t < NB) bpre[t] = woff + inc - v;
    if (t == 255) rows_end[0] = woff + inc;
}

__global__ __launch_bounds__(256) void scanC_kernel(const int* __restrict__ deg, const int* __restrict__ bpre,
                                                    int* __restrict__ rows, int* __restrict__ cursor) {
    int t = threadIdx.x, lane = t & 63, wv = t >> 6;
    int i = blockIdx.x * 256 + t;
    int v = (i < NN) ? deg[i] : 0;
    int inc = v;
#pragma unroll
    for (int off = 1; off < 64; off <<= 1) {
        int u = __shfl_up(inc, off, 64);
        if (lane >= off) inc += u;
    }
    __shared__ int wsum[4];
    if (lane == 63) wsum[wv] = inc;
    __syncthreads();
    int woff = bpre[blockIdx.x];
    for (int k = 0; k < wv; ++k) woff += wsum[k];
    int excl = woff + inc - v;
    if (i < NN) { rows[i] = excl; cursor[i] = excl; }
}

// ---------------- scatter edges into CSR-by-dst ----------------
__global__ void scatter_kernel(const int* __restrict__ src, const int* __restrict__ dst,
                               int* __restrict__ cursor, int* __restrict__ esrc) {
    int e = blockIdx.x * 256 + threadIdx.x;
    if (e < NE) {
        int d = dst[e];
        int pos = atomicAdd(&cursor[d], 1);
        esrc[pos] = src[e];
    }
}

// =============== GEMM v3: B-stationary LDS, A in registers, LDS-staged coalesced epilogue ====
// block = 128 rows x 128 cols; 4 waves x 32 rows.
template<bool USE_BF>
__global__ __launch_bounds__(256, 2) void gemm2_kernel(
    const u16* __restrict__ xbf, const float* __restrict__ xf, const u16* __restrict__ wT,
    const float* __restrict__ Wb, const float* __restrict__ Ub, const float* __restrict__ Vb,
    u16* __restrict__ WVh, float* __restrict__ Uh) {
    __shared__ __align__(16) u16 Bs[128 * 256];   // 64 KB (B tile; reused as C tile)

    int rb = blockIdx.x * 128;
    int cgy = blockIdx.y;                 // 0..5, 128 cols each
    int cbg = cgy * 128;                  // global col base in [0,768)
    int t = threadIdx.x, lane = t & 63, w = t >> 6;

    // ---- A: 16 fragments (2 row-groups x 8 k-steps) straight to VGPRs ----
    int arow = rb + w * 32 + (lane & 15);
    short8 afr[2][8];
    if (USE_BF) {
#pragma unroll
        for (int rg = 0; rg < 2; ++rg)
#pragma unroll
            for (int ks = 0; ks < 8; ++ks)
                afr[rg][ks] = *(const short8*)(xbf + (size_t)(arow + rg * 16) * 256 + ks * 32 + (lane >> 4) * 8);
    } else {
#pragma unroll
        for (int rg = 0; rg < 2; ++rg)
#pragma unroll
            for (int ks = 0; ks < 8; ++ks) {
                int row = arow + rg * 16;
                const float* p = xf + ((size_t)(row < NN ? row : 0)) * 256 + ks * 32 + (lane >> 4) * 8;
                floatx4 f0 = *(const floatx4*)(p);
                floatx4 f1 = *(const floatx4*)(p + 4);
                uint4 pk;
                pk.x = pack_bf(f0[0], f0[1]);
                pk.y = pack_bf(f0[2], f0[3]);
                pk.z = pack_bf(f1[0], f1[1]);
                pk.w = pack_bf(f1[2], f1[3]);
                afr[rg][ks] = *(short8*)&pk;
            }
    }

    // ---- B: stage 64KB once; each gl_lds16 covers 1KB = 2 cols (512B each) ----
#pragma unroll
    for (int i = 0; i < 16; ++i) {
        int ci = (w * 16 + i) * 2 + (lane >> 5);           // col 0..127
        int q = (lane & 31) ^ (ci & 7);                    // source quad (involution)
        gl_lds16(wT + (size_t)(cbg + ci) * 256 + q * 8, Bs + (w * 16 + i) * 512);
    }
    __syncthreads();

    // ---- compute: 64 ds_read_b128, 128 MFMA per wave, no barriers ----
    floatx4 acc[2][8] = {};
#pragma unroll
    for (int ks = 0; ks < 8; ++ks) {
#pragma unroll
        for (int cf = 0; cf < 8; ++cf) {
            int ci = cf * 16 + (lane & 15);
            int q = (ks * 4 + (lane >> 4)) ^ (ci & 7);
            short8 bfrag = *(const short8*)(Bs + ci * 256 + q * 8);
            acc[0][cf] = __builtin_amdgcn_mfma_f32_16x16x32_bf16(afr[0][ks], bfrag, acc[0][cf], 0, 0, 0);
            acc[1][cf] = __builtin_amdgcn_mfma_f32_16x16x32_bf16(afr[1][ks], bfrag, acc[1][cf], 0, 0, 0);
        }
    }

    // ---- epilogue: stage C tile in LDS (reuse Bs), stream out coalesced ----
    int g = cbg >> 8;                    // 0,0,1,1,2,2 -> W,W,U,U,V,V
    int cloc = cbg & 255;                // 0 or 128
    const float* bias = (g == 0) ? Wb : ((g == 1) ? Ub : Vb);

    __syncthreads();                     // all Bs reads done before overwrite

    if (g == 1) {
        // Uh: f32 tile, 128x128x4B = 64KB exactly
        float* Ct = (float*)Bs;
#pragma unroll
        for (int rg = 0; rg < 2; ++rg)
#pragma unroll
            for (int cf = 0; cf < 8; ++cf) {
                int col = cf * 16 + (lane & 15);
                float bv = bias[cloc + col];
#pragma unroll
                for (int r = 0; r < 4; ++r) {
                    int rl = w * 32 + rg * 16 + (lane >> 4) * 4 + r;
                    Ct[rl * 128 + col] = acc[rg][cf][r] + bv;
                }
            }
        __syncthreads();
        int row = t >> 1, half = t & 1;
        int grow = rb + row;
        if (grow < NN) {
            const uint4* srcp = (const uint4*)(Ct + row * 128 + half * 64);
            float* dstp = Uh + (size_t)grow * 256 + cloc + half * 64;
#pragma unroll
            for (int k = 0; k < 16; ++k)
                *(uint4*)(dstp + k * 4) = srcp[k];
        }
    } else {
        // W/V: bf16 tile, 128x128x2B = 32KB
        u16* Ct = (u16*)Bs;
#pragma unroll
        for (int rg = 0; rg < 2; ++rg)
#pragma unroll
            for (int cf = 0; cf < 8; ++cf) {
                int col = cf * 16 + (lane & 15);
                float bv = bias[cloc + col];
#pragma unroll
                for (int r = 0; r < 4; ++r) {
                    int rl = w * 32 + rg * 16 + (lane >> 4) * 4 + r;
                    Ct[rl * 128 + col] = f2bf(acc[rg][cf][r] + bv);
                }
            }
        __syncthreads();
        int row = t >> 1, half = t & 1;
        int grow = rb + row;
        if (grow < NN) {
            const uint4* srcp = (const uint4*)(Ct + row * 128 + half * 64);
            u16* dstp = WVh + (size_t)grow * 512 + (g == 2 ? 256 : 0) + cloc + half * 64;
#pragma unroll
            for (int k = 0; k < 8; ++k)
                *(uint4*)(dstp + k * 8) = srcp[k];
        }
    }
}

// ---------------- node-centric aggregate + LN + ReLU + residual ----------------
__global__ __launch_bounds__(256) void node_kernel(
    const u16* __restrict__ WVh, const float* __restrict__ x,
    const int* __restrict__ rows, const int* __restrict__ esrc,
    const float* __restrict__ attn_l, const float* __restrict__ attn_r,
    const float* __restrict__ gamma, const float* __restrict__ beta,
    float* inout) {
    int wv = threadIdx.x >> 6, lane = threadIdx.x & 63;
    int v = blockIdx.x * 4 + wv;
    if (v >= NN) return;
    int c0 = lane * 4;

    const float NL2E = -1.44269504f;    // -log2(e)
    floatx4 alv = *(const floatx4*)(attn_l + c0);
    floatx4 arv = *(const floatx4*)(attn_r + c0);
    uint2 wvv = *(const uint2*)(WVh + (size_t)v * 512 + c0);
    float al2[4] = { alv[0] * NL2E, alv[1] * NL2E, alv[2] * NL2E, alv[3] * NL2E };
    float td2[4] = { bf_lo(wvv.x) * arv[0] * NL2E, bf_hi(wvv.x) * arv[1] * NL2E,
                     bf_lo(wvv.y) * arv[2] * NL2E, bf_hi(wvv.y) * arv[3] * NL2E };

    float acc_h[4] = {0.f, 0.f, 0.f, 0.f};
    float acc_s[4] = {0.f, 0.f, 0.f, 0.f};

    auto edge = [&](uint2 wu, uint2 vu) {
        float wf[4] = { bf_lo(wu.x), bf_hi(wu.x), bf_lo(wu.y), bf_hi(wu.y) };
        float vf[4] = { bf_lo(vu.x), bf_hi(vu.x), bf_lo(vu.y), bf_hi(vu.y) };
#pragma unroll
        for (int j = 0; j < 4; ++j) {
            float m = fmaf(wf[j], al2[j], td2[j]);
            float s = __builtin_amdgcn_rcpf(1.0f + EXP2F(m));
            acc_s[j] += s;
            acc_h[j] = fmaf(s, vf[j], acc_h[j]);
        }
    };

    int e = rows[v], e1 = rows[v + 1];
    for (; e + 8 <= e1; e += 8) {
        int us[8];
#pragma unroll
        for (int q = 0; q < 8; ++q) us[q] = esrc[e + q];
        uint2 wu[8], vu[8];
#pragma unroll
        for (int q = 0; q < 8; ++q) {
            const u16* p = WVh + (size_t)us[q] * 512 + c0;
            wu[q] = *(const uint2*)p;
            vu[q] = *(const uint2*)(p + 256);
        }
#pragma unroll
        for (int q = 0; q < 8; ++q) edge(wu[q], vu[q]);
    }
    for (; e + 2 <= e1; e += 2) {
        int ua = esrc[e], ub = esrc[e + 1];
        const u16* pa = WVh + (size_t)ua * 512 + c0;
        const u16* pb = WVh + (size_t)ub * 512 + c0;
        uint2 wa = *(const uint2*)pa, va = *(const uint2*)(pa + 256);
        uint2 wb = *(const uint2*)pb, vb = *(const uint2*)(pb + 256);
        edge(wa, va); edge(wb, vb);
    }
    for (; e < e1; ++e) {
        int u = esrc[e];
        const u16* p = WVh + (size_t)u * 512 + c0;
        uint2 wu = *(const uint2*)p, vu = *(const uint2*)(p + 256);
        edge(wu, vu);
    }

    floatx4 uh = *(const floatx4*)(inout + (size_t)v * 256 + c0);
    float h[4];
#pragma unroll
    for (int j = 0; j < 4; ++j)
        h[j] = uh[j] + acc_h[j] * __builtin_amdgcn_rcpf(acc_s[j] + 1e-6f);

    float s01 = h[0] + h[1] + h[2] + h[3];
#pragma unroll
    for (int m = 32; m; m >>= 1) s01 += __shfl_xor(s01, m, 64);
    float mu = s01 * (1.0f / 256.0f);
    float d[4] = { h[0] - mu, h[1] - mu, h[2] - mu, h[3] - mu };
    float sq = d[0] * d[0] + d[1] * d[1] + d[2] * d[2] + d[3] * d[3];
#pragma unroll
    for (int m = 32; m; m >>= 1) sq += __shfl_xor(sq, m, 64);
    float inv = rsqrtf(sq * (1.0f / 256.0f) + 1e-6f);

    floatx4 gm = *(const floatx4*)(gamma + c0);
    floatx4 bt = *(const floatx4*)(beta + c0);
    floatx4 xr = *(const floatx4*)(x + (size_t)v * 256 + c0);
    floatx4 res;
#pragma unroll
    for (int j = 0; j < 4; ++j) {
        float y = d[j] * inv * gm[j] + bt[j];
        y = fmaxf(y, 0.0f);
        res[j] = xr[j] + y;
    }
    *(floatx4*)(inout + (size_t)v * 256 + c0) = res;
}

extern "C" void kernel_launch(void* const* d_in, const int* in_sizes, int n_in,
                              void* d_out, int out_size, void* d_ws, size_t ws_size,
                              hipStream_t stream) {
    const float* x       = (const float*)d_in[0];
    const int*   src     = (const int*)d_in[1];
    const int*   dst     = (const int*)d_in[2];
    const float* W_w     = (const float*)d_in[3];
    const float* W_b     = (const float*)d_in[4];
    const float* U_w     = (const float*)d_in[5];
    const float* U_b     = (const float*)d_in[6];
    const float* V_w     = (const float*)d_in[7];
    const float* V_b     = (const float*)d_in[8];
    const float* attn_l  = (const float*)d_in[9];
    const float* attn_r  = (const float*)d_in[10];
    const float* gamma   = (const float*)d_in[11];
    const float* beta    = (const float*)d_in[12];

    char* ws = (char*)d_ws;
    size_t off = 0;
    auto alloc = [&](size_t bytes) -> char* {
        char* p = ws + off;
        off += (bytes + 255) & ~(size_t)255;
        return p;
    };
    u16* WVh     = (u16*)alloc((size_t)NN * 512 * 2);     // Wh | Vh interleaved per node
    u16* wT      = (u16*)alloc((size_t)768 * 256 * 2);
    int* deg     = (int*)alloc((size_t)NN * 4);
    int* rows    = (int*)alloc((size_t)(NN + 1) * 4);
    int* cursor  = (int*)alloc((size_t)NN * 4);
    int* esrc    = (int*)alloc((size_t)NE * 4);
    int* bsum    = (int*)alloc((size_t)NB * 4);
    int* bpre    = (int*)alloc((size_t)NB * 4);
    u16* xbf     = (u16*)alloc((size_t)NROWPAD * 256 * 2);   // optional (last)
    bool use_bf  = (ws_size >= off);

    float* Uh_f32 = (float*)d_out;   // staged in d_out, overwritten by node_kernel

    hipMemsetAsync(deg, 0, (size_t)NN * 4, stream);

    int xb = use_bf ? XCVT_BLOCKS : 0;
    prep_kernel<<<xb + TW_BLOCKS + HIST_BLOCKS, 256, 0, stream>>>(
        x, xbf, W_w, U_w, V_w, wT, dst, deg, use_bf ? 1 : 0);

    scanA_kernel<<<NB, 256, 0, stream>>>(deg, bsum);
    scanB_kernel<<<1, 256, 0, stream>>>(bsum, bpre, rows + NN);
    scanC_kernel<<<NB, 256, 0, stream>>>(deg, bpre, rows, cursor);
    scatter_kernel<<<(NE + 255) / 256, 256, 0, stream>>>(src, dst, cursor, esrc);

    dim3 gg((NN + 127) / 128, 6);
    if (use_bf) {
        gemm2_kernel<true><<<gg, 256, 0, stream>>>(xbf, x, wT, W_b, U_b, V_b, WVh, Uh_f32);
    } else {
        gemm2_kernel<false><<<gg, 256, 0, stream>>>(nullptr, x, wT, W_b, U_b, V_b, WVh, Uh_f32);
    }

    node_kernel<<<(NN + 3) / 4, 256, 0, stream>>>(
        WVh, x, rows, esrc, attn_l, attn_r, gamma, beta, (float*)d_out);
}